// Round 14
// baseline (78.708 us; speedup 1.0000x reference)
//
#include <hip/hip_runtime.h>
#include <math.h>

#define UU 208
#define VV 176
#define NPIX (UU*VV)       // 36608
#define MASKBLKS 143
#define ROWBLKS 1664       // 26624 pair-rows / 16

typedef __attribute__((ext_vector_type(2))) float v2f;   // complex: .x=re, .y=im
typedef __attribute__((ext_vector_type(4))) float v4f;   // fwd twiddle: (c, s, -s, c)

__device__ __forceinline__ v2f mk2(float x, float y){ v2f r; r.x = x; r.y = y; return r; }
__device__ __forceinline__ v2f sp(float s){ v2f r; r.x = s; r.y = s; return r; }

template<bool INV>
__device__ __forceinline__ v2f cmulc(v2f a, float wx, float wy_fwd){
  const float wy = INV ? -wy_fwd : wy_fwd;
  return sp(a.x) * mk2(wx, wy) + sp(a.y) * mk2(-wy, wx);
}
// forward mul by table entry t=(c,s,-s,c): a*w
__device__ __forceinline__ v2f cmulw4(v2f a, v4f t){
  return sp(a.x) * mk2(t.x, t.y) + sp(a.y) * mk2(t.z, t.w);
}
// inverse mul (by conj(w)) from the SAME forward table
__device__ __forceinline__ v2f cmulw4i(v2f a, v4f t){
  return sp(a.x) * mk2(t.x, t.z) + sp(a.y) * mk2(t.y, t.w);
}

template<bool INV>
__device__ __forceinline__ void dft4(v2f& x0, v2f& x1, v2f& x2, v2f& x3){
  v2f s0 = x0 + x2, d0 = x0 - x2;
  v2f s1 = x1 + x3, d1 = x1 - x3;
  v2f jd1;
  if (INV){ jd1.x = -d1.y; jd1.y =  d1.x; }
  else    { jd1.x =  d1.y; jd1.y = -d1.x; }
  x0 = s0 + s1; x2 = s0 - s1;
  x1 = d0 + jd1; x3 = d0 - jd1;
}

// 16-point FFT, input x[n] in v[n], output Y[j] at v[4*(j&3) + (j>>2)]
template<bool INV>
__device__ __forceinline__ void fft16(v2f v[16]){
  dft4<INV>(v[0], v[4], v[8],  v[12]);
  dft4<INV>(v[1], v[5], v[9],  v[13]);
  dft4<INV>(v[2], v[6], v[10], v[14]);
  dft4<INV>(v[3], v[7], v[11], v[15]);
  const float C1 = 0.92387953251128674f;
  const float S1 = 0.38268343236508978f;
  const float R2 = 0.70710678118654752f;
  v[5]  = cmulc<INV>(v[5],  C1, -S1);
  v[9]  = cmulc<INV>(v[9],  R2, -R2);
  v[13] = cmulc<INV>(v[13], S1, -C1);
  v[6]  = cmulc<INV>(v[6],  R2, -R2);
  v[10] = cmulc<INV>(v[10], 0.f, -1.f);
  v[14] = cmulc<INV>(v[14], -R2, -R2);
  v[7]  = cmulc<INV>(v[7],  S1, -C1);
  v[11] = cmulc<INV>(v[11], -R2, -R2);
  v[15] = cmulc<INV>(v[15], -C1,  S1);
  dft4<INV>(v[0],  v[1],  v[2],  v[3]);
  dft4<INV>(v[4],  v[5],  v[6],  v[7]);
  dft4<INV>(v[8],  v[9],  v[10], v[11]);
  dft4<INV>(v[12], v[13], v[14], v[15]);
}

// ---- odd-N DFT via conjugate-pair real-twiddle decomposition ----
template<int N, bool INV>
__device__ __forceinline__ void dftN(const v2f* __restrict__ t, v2f* __restrict__ F,
                                     const v2f* __restrict__ cs){
  v2f a = t[0];
  #pragma unroll
  for (int n = 1; n < N; n++) a += t[n];
  F[0] = a;
  #pragma unroll
  for (int k = 1; k <= N/2; k++){
    v2f C = t[0], S = sp(0.f);
    #pragma unroll
    for (int n = 1; n < N; n++){
      const int idx = (n * k) % N;
      C += t[n] * sp(cs[idx].x);
      S += t[n] * sp(cs[idx].y);
    }
    v2f ssw; ssw.x = S.y; ssw.y = -S.x;   // = -i*S
    if (!INV){ F[k] = C + ssw; F[N-k] = C - ssw; }
    else     { F[k] = C - ssw; F[N-k] = C + ssw; }
  }
}

__device__ __forceinline__ unsigned sortable(float f){
  unsigned u = __float_as_uint(f);
  return (u & 0x80000000u) ? ~u : (u | 0x80000000u);
}

// parallel bucket-find over PER*256 global bins; updates *kRef to offset within bucket
template<int PER>
__device__ __forceinline__ unsigned findNk(const unsigned* __restrict__ bins_g,
                                           unsigned* sWS, unsigned* sRes, unsigned* kRef){
  const int t = threadIdx.x, lane = t & 63, wv = t >> 6;
  unsigned c[PER]; unsigned s = 0;
  #pragma unroll
  for (int j = 0; j < PER; j++){ c[j] = bins_g[t*PER + j]; s += c[j]; }
  unsigned v = s;
  #pragma unroll
  for (int d = 1; d < 64; d <<= 1){
    unsigned u = __shfl_up(v, d, 64);
    if (lane >= d) v += u;
  }
  if (lane == 63) sWS[wv] = v;
  __syncthreads();
  unsigned woff = 0;
  #pragma unroll
  for (int j = 0; j < 3; j++) woff += (j < wv) ? sWS[j] : 0u;
  unsigned incl = v + woff, excl = incl - s;
  unsigned k = *kRef;
  if (k >= excl && k < incl){
    unsigned kk = k - excl; unsigned b = (unsigned)(t*PER);
    #pragma unroll
    for (int j = 0; j < PER; j++){
      if (kk < c[j]){ b = (unsigned)(t*PER + j); break; }
      kk -= c[j];
    }
    sRes[0] = b; sRes[1] = kk;
  }
  __syncthreads();
  *kRef = sRes[1];
  unsigned b = sRes[0];
  __syncthreads();
  return b;
}

// ======== rowFFT (blocks 0..1663) + mask r-values & 11-bit level-0 hist (last 143) ========
__global__ __launch_bounds__(256) void rowfft_mask(const float* __restrict__ x, v2f* __restrict__ freq,
                                                   const float* __restrict__ kin, float* __restrict__ rbuf,
                                                   unsigned* __restrict__ bins0){
  const double PI2 = 6.283185307179586476925286766559;
  __shared__ v4f wf[VV];
  __shared__ v2f cs11[11];
  __shared__ v2f mid[16][177];
  if (blockIdx.x >= ROWBLKS){
    // ---- mask block: r[l,k] (fp64, Chebyshev, symmetry-exact) + 2048-bin level-0 hist ----
    unsigned* h = (unsigned*)&mid[0][0];     // 2048 bins alias mid
    int i = (blockIdx.x - ROWBLKS) * 256 + threadIdx.x;  // covers NPIX exactly
    int l = i / VV, k = i - l * VV;
    double c1, s1, c2, s2;
    { double a = PI2 * (double)k / (double)VV; c1 = cos(a); s1 = sin(a); }
    { double a = PI2 * (double)l / (double)UU; c2 = cos(a); s2 = sin(a); }
    double cA[6], sA[6], cB[6], sB[6];
    cA[0] = 1.0; sA[0] = 0.0; cA[1] = c1; sA[1] = s1;
    cB[0] = 1.0; sB[0] = 0.0; cB[1] = c2; sB[1] = s2;
    #pragma unroll
    for (int m = 2; m < 6; m++){
      cA[m] = 2.0*c1*cA[m-1] - cA[m-2];
      sA[m] = 2.0*c1*sA[m-1] - sA[m-2];
      cB[m] = 2.0*c2*cB[m-1] - cB[m-2];
      sB[m] = 2.0*c2*sB[m-1] - sB[m-2];
    }
    const int rm[6] = {0, 1, 2, 2, 1, 0};
    double P[3], Q[3];
    #pragma unroll
    for (int a = 0; a < 3; a++){
      P[a] = 0.0; Q[a] = 0.0;
      #pragma unroll
      for (int n = 0; n < 6; n++){
        double kv = (double)kin[a*3 + rm[n]];
        P[a] += kv * cB[n];
        Q[a] += kv * sB[n];
      }
    }
    double s = 0.0;
    #pragma unroll
    for (int m = 0; m < 6; m++)
      s += cA[m]*P[rm[m]] - sA[m]*Q[rm[m]];
    float val = (float)(s / 36.0);
    rbuf[i] = val;
    const unsigned uval = sortable(val);
    #pragma unroll
    for (int j = 0; j < 8; j++) h[threadIdx.x*8 + j] = 0u;
    __syncthreads();
    atomicAdd(&h[uval >> 21], 1u);
    __syncthreads();
    #pragma unroll
    for (int j = 0; j < 8; j++){
      unsigned hv = h[threadIdx.x*8 + j];
      if (hv) atomicAdd(&bins0[threadIdx.x*8 + j], hv);
    }
    return;
  }
  // ---- rowFFT block (paired planes, wave-autonomous) ----
  { int i = threadIdx.x;
    if (i < VV){
      double a = -PI2 * (double)i / (double)VV;
      float c = (float)cos(a), s = (float)sin(a);
      v4f f; f.x = c; f.y = s; f.z = -s; f.w = c; wf[i] = f;
    }
    if (i < 11){
      double a = PI2 * (double)i / 11.0;
      cs11[i] = mk2((float)cos(a), (float)sin(a));
    } }
  const int gr = threadIdx.x >> 4, ln = threadIdx.x & 15;
  const int row = blockIdx.x * 16 + gr;          // < 26624
  const int p = row / UU, rr = row - p * UU;
  const float* xr1 = x + ((size_t)(2*p) * UU + rr) * VV;
  const float* xr2 = xr1 + (size_t)NPIX;
  v2f* fr = freq + (size_t)row * VV;
  __syncthreads();                                // tables ready (only barrier)
  if (ln < 11){
    v2f v[16];
    #pragma unroll
    for (int a = 0; a < 16; a++) v[a] = mk2(xr1[11*a + ln], xr2[11*a + ln]);
    fft16<false>(v);
    #pragma unroll
    for (int j = 0; j < 16; j++)
      mid[gr][j*11 + ln] = cmulw4(v[4*(j&3) + (j>>2)], wf[ln*j]);
  }
  v2f t[11], F[11];
  #pragma unroll
  for (int n2 = 0; n2 < 11; n2++) t[n2] = mid[gr][ln*11 + n2];
  dftN<11,false>(t, F, cs11);
  #pragma unroll
  for (int k2 = 0; k2 < 11; k2++) fr[ln + 16*k2] = F[k2];
}

// ======== level-1: bits 20..10 (2048 bins) ========
__global__ __launch_bounds__(256) void hist1(const float* __restrict__ rbuf,
                                             const unsigned* __restrict__ bins0,
                                             unsigned* __restrict__ bins1){
  __shared__ unsigned h[2048];
  __shared__ unsigned sWS[4], sRes[2];
  #pragma unroll
  for (int j = 0; j < 8; j++) h[threadIdx.x*8 + j] = 0u;
  unsigned kk = 18304u;
  unsigned b0 = findNk<8>(bins0, sWS, sRes, &kk);   // internal syncs cover h zeroing
  int i = blockIdx.x * 256 + threadIdx.x;
  unsigned uval = sortable(rbuf[i]);
  if ((uval >> 21) == b0) atomicAdd(&h[(uval >> 10) & 2047u], 1u);
  __syncthreads();
  #pragma unroll
  for (int j = 0; j < 8; j++){
    unsigned hv = h[threadIdx.x*8 + j];
    if (hv) atomicAdd(&bins1[threadIdx.x*8 + j], hv);
  }
}

// ======== level-2: bits 9..0 (1024 bins) ========
__global__ __launch_bounds__(256) void hist2(const float* __restrict__ rbuf,
                                             const unsigned* __restrict__ bins0,
                                             const unsigned* __restrict__ bins1,
                                             unsigned* __restrict__ bins2){
  __shared__ unsigned h[1024];
  __shared__ unsigned sWS[4], sRes[2];
  #pragma unroll
  for (int j = 0; j < 4; j++) h[threadIdx.x*4 + j] = 0u;
  unsigned kk = 18304u;
  unsigned b0 = findNk<8>(bins0, sWS, sRes, &kk);
  unsigned b1 = findNk<8>(bins1, sWS, sRes, &kk);
  int i = blockIdx.x * 256 + threadIdx.x;
  unsigned uval = sortable(rbuf[i]);
  if ((uval >> 10) == ((b0 << 11) | b1)) atomicAdd(&h[uval & 1023u], 1u);
  __syncthreads();
  #pragma unroll
  for (int j = 0; j < 4; j++){
    unsigned hv = h[threadIdx.x*4 + j];
    if (hv) atomicAdd(&bins2[threadIdx.x*4 + j], hv);
  }
}

// ======== final: 3 bin scans only (no rbuf pass), writes threshold ========
__global__ __launch_bounds__(256) void thr_final(const unsigned* __restrict__ bins0,
                                                 const unsigned* __restrict__ bins1,
                                                 const unsigned* __restrict__ bins2,
                                                 float* __restrict__ thrOut){
  __shared__ unsigned sWS[4], sRes[2];
  unsigned kk = 18304u;
  unsigned b0 = findNk<8>(bins0, sWS, sRes, &kk);
  unsigned b1 = findNk<8>(bins1, sWS, sRes, &kk);
  unsigned b2 = findNk<4>(bins2, sWS, sRes, &kk);
  if (threadIdx.x == 0){
    unsigned u = (b0 << 21) | (b1 << 10) | b2;
    u = (u & 0x80000000u) ? (u ^ 0x80000000u) : ~u;
    thrOut[0] = __uint_as_float(u);
  }
}

// ======== fused column FFT * mask * column IFFT: role-major, barriered (R10 form) ========
__global__ __launch_bounds__(256) void colfft(v2f* __restrict__ freq,
                                              const float* __restrict__ rbuf, const float* __restrict__ thrp){
  __shared__ v4f wf[UU];
  __shared__ v2f cs13[13];
  __shared__ v2f buf[UU*17];
  { int i = threadIdx.x;
    const double PI2 = 6.283185307179586476925286766559;
    if (i < UU){
      double a = -PI2 * (double)i / (double)UU;
      float c = (float)cos(a), s = (float)sin(a);
      v4f f; f.x = c; f.y = s; f.z = -s; f.w = c; wf[i] = f;
    }
    if (i < 13){
      double a = PI2 * (double)i / 13.0;
      cs13[i] = mk2((float)cos(a), (float)sin(a));
    } }
  const int role = threadIdx.x >> 4, c = threadIdx.x & 15;
  const int img = blockIdx.x / 11;                // paired plane [0,128)
  const int v0 = (blockIdx.x - img*11) << 4;
  v2f* base = freq + (size_t)img * NPIX + v0 + c;
  const float thr = thrp[0];
  __syncthreads();
  // Phase A: inner 16-pt forward DFTs (n1 = role < 13) -> buf rows j*13+role
  if (role < 13){
    v2f v[16];
    #pragma unroll
    for (int a = 0; a < 16; a++) v[a] = base[(13*a + role)*VV];
    fft16<false>(v);
    #pragma unroll
    for (int j = 0; j < 16; j++)
      buf[(j*13 + role)*17 + c] = cmulw4(v[4*(j&3) + (j>>2)], wf[role*j]);
  }
  __syncthreads();
  // Phase B: 13-pt DFT (k1 = role), mask, stage in regs
  v2f F[13];
  {
    v2f t[13];
    #pragma unroll
    for (int n2 = 0; n2 < 13; n2++) t[n2] = buf[(role*13 + n2)*17 + c];
    dftN<13,false>(t, F, cs13);
    #pragma unroll
    for (int k2 = 0; k2 < 13; k2++){
      int u = role + 16*k2;
      float m = (rbuf[u*VV + v0 + c] > thr) ? 1.0f : 0.0f;
      F[k2] *= sp(m);
    }
  }
  __syncthreads();
  #pragma unroll
  for (int k2 = 0; k2 < 13; k2++) buf[(role + 16*k2)*17 + c] = F[k2];
  __syncthreads();
  // Phase C: inner 16-pt inverse DFTs
  if (role < 13){
    v2f v[16];
    #pragma unroll
    for (int a = 0; a < 16; a++) v[a] = buf[(13*a + role)*17 + c];
    fft16<true>(v);
    #pragma unroll
    for (int j = 0; j < 16; j++)
      buf[(j*13 + role)*17 + c] = cmulw4i(v[4*(j&3) + (j>>2)], wf[role*j]);
  }
  __syncthreads();
  // Phase D: 13-pt inverse DFT, write spatial column back (unscaled)
  {
    v2f t[13], G[13];
    #pragma unroll
    for (int n2 = 0; n2 < 13; n2++) t[n2] = buf[(role*13 + n2)*17 + c];
    dftN<13,true>(t, G, cs13);
    #pragma unroll
    for (int k2 = 0; k2 < 13; k2++)
      base[(role + 16*k2)*VV] = G[k2];
  }
}

// ======== row IFFT + split pair + abs + scale, wave-autonomous ========
__global__ __launch_bounds__(256) void rowifft_abs(const v2f* __restrict__ freq, float* __restrict__ out){
  __shared__ v4f wf[VV];
  __shared__ v2f cs11[11];
  __shared__ v2f mid[16][177];
  { int i = threadIdx.x;
    const double PI2 = 6.283185307179586476925286766559;
    if (i < VV){
      double a = -PI2 * (double)i / (double)VV;
      float c = (float)cos(a), s = (float)sin(a);
      v4f f; f.x = c; f.y = s; f.z = -s; f.w = c; wf[i] = f;
    }
    if (i < 11){
      double a = PI2 * (double)i / 11.0;
      cs11[i] = mk2((float)cos(a), (float)sin(a));
    } }
  const int gr = threadIdx.x >> 4, ln = threadIdx.x & 15;
  const int row = blockIdx.x * 16 + gr;
  const int p = row / UU, rr = row - p * UU;
  const v2f* fr = freq + (size_t)row * VV;
  float* orow1 = out + ((size_t)(2*p) * UU + rr) * VV;
  float* orow2 = orow1 + (size_t)NPIX;
  __syncthreads();
  if (ln < 11){
    v2f v[16];
    #pragma unroll
    for (int a = 0; a < 16; a++) v[a] = fr[11*a + ln];
    fft16<true>(v);
    #pragma unroll
    for (int j = 0; j < 16; j++)
      mid[gr][j*11 + ln] = cmulw4i(v[4*(j&3) + (j>>2)], wf[ln*j]);
  }
  v2f t[11], G[11];
  #pragma unroll
  for (int n2 = 0; n2 < 11; n2++) t[n2] = mid[gr][ln*11 + n2];
  dftN<11,true>(t, G, cs11);
  #pragma unroll
  for (int k2 = 0; k2 < 11; k2++){
    orow1[ln + 16*k2] = fabsf(G[k2].x) * (1.0f / 36608.0f);
    orow2[ln + 16*k2] = fabsf(G[k2].y) * (1.0f / 36608.0f);
  }
}

extern "C" void kernel_launch(void* const* d_in, const int* in_sizes, int n_in,
                              void* d_out, int out_size, void* d_ws, size_t ws_size,
                              hipStream_t stream){
  const float* x   = (const float*)d_in[0];   // (32,8,208,176) f32
  const float* kin = (const float*)d_in[1];   // (3,3,1,1) f32
  float* out = (float*)d_out;
  char* ws = (char*)d_ws;
  v2f*      freq  = (v2f*)ws;                     // 37,486,592 B
  float*    rbuf  = (float*)(ws + 37486592);      // 146,432 B
  float*    thr   = (float*)(ws + 37633024);      // 16 B
  unsigned* bins0 = (unsigned*)(ws + 37633040);   // 2048 u32
  unsigned* bins1 = bins0 + 2048;                 // 2048 u32
  unsigned* bins2 = bins1 + 2048;                 // 1024 u32

  hipMemsetAsync(bins0, 0, (2048 + 2048 + 1024) * 4, stream);
  hipLaunchKernelGGL(rowfft_mask, dim3(ROWBLKS + MASKBLKS), dim3(256), 0, stream,
                     x, freq, kin, rbuf, bins0);
  hipLaunchKernelGGL(hist1,       dim3(143),  dim3(256), 0, stream, rbuf, bins0, bins1);
  hipLaunchKernelGGL(hist2,       dim3(143),  dim3(256), 0, stream, rbuf, bins0, bins1, bins2);
  hipLaunchKernelGGL(thr_final,   dim3(1),    dim3(256), 0, stream, bins0, bins1, bins2, thr);
  hipLaunchKernelGGL(colfft,      dim3(1408), dim3(256), 0, stream, freq, rbuf, thr);
  hipLaunchKernelGGL(rowifft_abs, dim3(1664), dim3(256), 0, stream, freq, out);
}

// Round 15
// 69.327 us; speedup vs baseline: 1.1353x; 1.1353x over previous
//
#include <hip/hip_runtime.h>
#include <math.h>

#define UU 208
#define VV 176
#define NPIX (UU*VV)       // 36608
#define MASKBLKS 143
#define ROWBLKS 1664       // 26624 pair-rows / 16

typedef __attribute__((ext_vector_type(2))) float v2f;   // complex: .x=re, .y=im
typedef __attribute__((ext_vector_type(4))) float v4f;   // fwd twiddle: (c, s, -s, c)

__device__ __forceinline__ v2f mk2(float x, float y){ v2f r; r.x = x; r.y = y; return r; }
__device__ __forceinline__ v2f sp(float s){ v2f r; r.x = s; r.y = s; return r; }

template<bool INV>
__device__ __forceinline__ v2f cmulc(v2f a, float wx, float wy_fwd){
  const float wy = INV ? -wy_fwd : wy_fwd;
  return sp(a.x) * mk2(wx, wy) + sp(a.y) * mk2(-wy, wx);
}
// forward mul by table entry t=(c,s,-s,c): a*w
__device__ __forceinline__ v2f cmulw4(v2f a, v4f t){
  return sp(a.x) * mk2(t.x, t.y) + sp(a.y) * mk2(t.z, t.w);
}
// inverse mul (by conj(w)) from the SAME forward table
__device__ __forceinline__ v2f cmulw4i(v2f a, v4f t){
  return sp(a.x) * mk2(t.x, t.z) + sp(a.y) * mk2(t.y, t.w);
}

template<bool INV>
__device__ __forceinline__ void dft4(v2f& x0, v2f& x1, v2f& x2, v2f& x3){
  v2f s0 = x0 + x2, d0 = x0 - x2;
  v2f s1 = x1 + x3, d1 = x1 - x3;
  v2f jd1;
  if (INV){ jd1.x = -d1.y; jd1.y =  d1.x; }
  else    { jd1.x =  d1.y; jd1.y = -d1.x; }
  x0 = s0 + s1; x2 = s0 - s1;
  x1 = d0 + jd1; x3 = d0 - jd1;
}

// 16-point FFT, input x[n] in v[n], output Y[j] at v[4*(j&3) + (j>>2)]
template<bool INV>
__device__ __forceinline__ void fft16(v2f v[16]){
  dft4<INV>(v[0], v[4], v[8],  v[12]);
  dft4<INV>(v[1], v[5], v[9],  v[13]);
  dft4<INV>(v[2], v[6], v[10], v[14]);
  dft4<INV>(v[3], v[7], v[11], v[15]);
  const float C1 = 0.92387953251128674f;
  const float S1 = 0.38268343236508978f;
  const float R2 = 0.70710678118654752f;
  v[5]  = cmulc<INV>(v[5],  C1, -S1);
  v[9]  = cmulc<INV>(v[9],  R2, -R2);
  v[13] = cmulc<INV>(v[13], S1, -C1);
  v[6]  = cmulc<INV>(v[6],  R2, -R2);
  v[10] = cmulc<INV>(v[10], 0.f, -1.f);
  v[14] = cmulc<INV>(v[14], -R2, -R2);
  v[7]  = cmulc<INV>(v[7],  S1, -C1);
  v[11] = cmulc<INV>(v[11], -R2, -R2);
  v[15] = cmulc<INV>(v[15], -C1,  S1);
  dft4<INV>(v[0],  v[1],  v[2],  v[3]);
  dft4<INV>(v[4],  v[5],  v[6],  v[7]);
  dft4<INV>(v[8],  v[9],  v[10], v[11]);
  dft4<INV>(v[12], v[13], v[14], v[15]);
}

// ---- odd-N DFT, FOLDED conjugate-pair form (input + output symmetry) ----
// u[n]=t[n]+t[N-n], w[n]=t[n]-t[N-n]:
//   C_k = t0 + sum u[n] cos(2pi nk/N);  S_k = sum w[n] sin(2pi nk/N)
//   F[k] = C - iS,  F[N-k] = C + iS   (forward; conj swap for inverse)
template<int N, bool INV>
__device__ __forceinline__ void dftN(const v2f* __restrict__ t, v2f* __restrict__ F,
                                     const v2f* __restrict__ cs){
  const int H = N/2;
  v2f u[H], w[H];
  #pragma unroll
  for (int n = 1; n <= H; n++){ u[n-1] = t[n] + t[N-n]; w[n-1] = t[n] - t[N-n]; }
  v2f a = t[0];
  #pragma unroll
  for (int n = 0; n < H; n++) a += u[n];
  F[0] = a;
  #pragma unroll
  for (int k = 1; k <= H; k++){
    v2f C = t[0], S = sp(0.f);
    #pragma unroll
    for (int n = 1; n <= H; n++){
      const int idx = (n * k) % N;
      C += u[n-1] * sp(cs[idx].x);
      S += w[n-1] * sp(cs[idx].y);
    }
    v2f ssw; ssw.x = S.y; ssw.y = -S.x;   // = -i*S
    if (!INV){ F[k] = C + ssw; F[N-k] = C - ssw; }
    else     { F[k] = C - ssw; F[N-k] = C + ssw; }
  }
}

__device__ __forceinline__ unsigned sortable(float f){
  unsigned u = __float_as_uint(f);
  return (u & 0x80000000u) ? ~u : (u | 0x80000000u);
}

// parallel bucket find: 256 threads, bins_g[256]
__device__ __forceinline__ unsigned find_bucket(const unsigned* __restrict__ bins_g,
                                                unsigned* sWS, unsigned* sB, unsigned* sK){
  const int t = threadIdx.x, lane = t & 63, wv = t >> 6;
  unsigned c = bins_g[t];
  unsigned v = c;
  #pragma unroll
  for (int d = 1; d < 64; d <<= 1){
    unsigned u = __shfl_up(v, d, 64);
    if (lane >= d) v += u;
  }
  if (lane == 63) sWS[wv] = v;
  __syncthreads();
  unsigned woff = 0;
  #pragma unroll
  for (int j = 0; j < 3; j++) woff += (j < wv) ? sWS[j] : 0u;
  unsigned incl = v + woff, excl = incl - c;
  unsigned k = *sK;
  __syncthreads();
  if (k >= excl && k < incl){ *sB = (unsigned)t; *sK = k - excl; }
  __syncthreads();
  return *sB;
}

// ======== rowFFT (blocks 0..1663) + mask r-values & level-0 hist (last 143) ========
__global__ __launch_bounds__(256) void rowfft_mask(const float* __restrict__ x, v2f* __restrict__ freq,
                                                   const float* __restrict__ kin, float* __restrict__ rbuf,
                                                   unsigned* __restrict__ bins24){
  const double PI2 = 6.283185307179586476925286766559;
  __shared__ v4f wf[VV];
  __shared__ v2f cs11[11];
  __shared__ v2f mid[16][177];
  if (blockIdx.x >= ROWBLKS){
    // ---- mask block: r[l,k] via Chebyshev recurrences (fp64, symmetry-exact) ----
    unsigned* h = (unsigned*)mid;     // reuse LDS
    h[threadIdx.x] = 0u;
    int i = (blockIdx.x - ROWBLKS) * 256 + threadIdx.x;  // covers NPIX exactly
    int l = i / VV, k = i - l * VV;
    double c1, s1, c2, s2;
    { double a = PI2 * (double)k / (double)VV; c1 = cos(a); s1 = sin(a); }
    { double a = PI2 * (double)l / (double)UU; c2 = cos(a); s2 = sin(a); }
    double cA[6], sA[6], cB[6], sB[6];
    cA[0] = 1.0; sA[0] = 0.0; cA[1] = c1; sA[1] = s1;
    cB[0] = 1.0; sB[0] = 0.0; cB[1] = c2; sB[1] = s2;
    #pragma unroll
    for (int m = 2; m < 6; m++){
      cA[m] = 2.0*c1*cA[m-1] - cA[m-2];
      sA[m] = 2.0*c1*sA[m-1] - sA[m-2];
      cB[m] = 2.0*c2*cB[m-1] - cB[m-2];
      sB[m] = 2.0*c2*sB[m-1] - sB[m-2];
    }
    const int rm[6] = {0, 1, 2, 2, 1, 0};
    double P[3], Q[3];
    #pragma unroll
    for (int a = 0; a < 3; a++){
      P[a] = 0.0; Q[a] = 0.0;
      #pragma unroll
      for (int n = 0; n < 6; n++){
        double kv = (double)kin[a*3 + rm[n]];
        P[a] += kv * cB[n];
        Q[a] += kv * sB[n];
      }
    }
    double s = 0.0;
    #pragma unroll
    for (int m = 0; m < 6; m++)
      s += cA[m]*P[rm[m]] - sA[m]*Q[rm[m]];
    float val = (float)(s / 36.0);
    rbuf[i] = val;
    __syncthreads();
    atomicAdd(&h[sortable(val) >> 24], 1u);
    __syncthreads();
    if (h[threadIdx.x]) atomicAdd(&bins24[threadIdx.x], h[threadIdx.x]);
    return;
  }
  // ---- rowFFT block (paired planes, wave-autonomous) ----
  { int i = threadIdx.x;
    if (i < VV){
      double a = -PI2 * (double)i / (double)VV;
      float c = (float)cos(a), s = (float)sin(a);
      v4f f; f.x = c; f.y = s; f.z = -s; f.w = c; wf[i] = f;
    }
    if (i < 11){
      double a = PI2 * (double)i / 11.0;
      cs11[i] = mk2((float)cos(a), (float)sin(a));
    } }
  const int gr = threadIdx.x >> 4, ln = threadIdx.x & 15;
  const int row = blockIdx.x * 16 + gr;          // < 26624
  const int p = row / UU, rr = row - p * UU;
  const float* xr1 = x + ((size_t)(2*p) * UU + rr) * VV;
  const float* xr2 = xr1 + (size_t)NPIX;
  v2f* fr = freq + (size_t)row * VV;
  __syncthreads();                                // tables ready (only barrier)
  if (ln < 11){
    v2f v[16];
    #pragma unroll
    for (int a = 0; a < 16; a++) v[a] = mk2(xr1[11*a + ln], xr2[11*a + ln]);
    fft16<false>(v);
    #pragma unroll
    for (int j = 0; j < 16; j++)
      mid[gr][j*11 + ln] = cmulw4(v[4*(j&3) + (j>>2)], wf[ln*j]);
  }
  v2f t[11], F[11];
  #pragma unroll
  for (int n2 = 0; n2 < 11; n2++) t[n2] = mid[gr][ln*11 + n2];
  dftN<11,false>(t, F, cs11);
  #pragma unroll
  for (int k2 = 0; k2 < 11; k2++) fr[ln + 16*k2] = F[k2];
}

// ---------------- radix-select refinement (parallel scans, multi-block) ----------------
template<int LEVEL>
__global__ __launch_bounds__(256) void hist_pass(const float* __restrict__ rbuf,
                                                 const unsigned* __restrict__ binsAll,
                                                 unsigned* __restrict__ binsOut){
  __shared__ unsigned h[256];
  __shared__ unsigned sWS[4];
  __shared__ unsigned sB, sK;
  if (threadIdx.x == 0) sK = 18304u;
  h[threadIdx.x] = 0u;
  __syncthreads();
  unsigned prefix = find_bucket(binsAll, sWS, &sB, &sK) << 24;
  if (LEVEL >= 2) prefix |= find_bucket(binsAll + 256, sWS, &sB, &sK) << 16;
  if (LEVEL >= 3) prefix |= find_bucket(binsAll + 512, sWS, &sB, &sK) << 8;
  const int SHIFT = 24 - 8*LEVEL;
  int i = blockIdx.x * 256 + threadIdx.x;
  unsigned u = sortable(rbuf[i]);
  if ((u >> (SHIFT + 8)) == (prefix >> (SHIFT + 8)))
    atomicAdd(&h[(u >> SHIFT) & 255u], 1u);
  __syncthreads();
  if (h[threadIdx.x]) atomicAdd(&binsOut[threadIdx.x], h[threadIdx.x]);
}

__global__ __launch_bounds__(256) void thr_final(const unsigned* __restrict__ binsAll,
                                                 float* __restrict__ thrOut){
  __shared__ unsigned sWS[4];
  __shared__ unsigned sB, sK;
  if (threadIdx.x == 0) sK = 18304u;
  __syncthreads();
  unsigned prefix = find_bucket(binsAll,       sWS, &sB, &sK) << 24;
  prefix |= find_bucket(binsAll + 256, sWS, &sB, &sK) << 16;
  prefix |= find_bucket(binsAll + 512, sWS, &sB, &sK) << 8;
  prefix |= find_bucket(binsAll + 768, sWS, &sB, &sK);
  if (threadIdx.x == 0){
    unsigned u = prefix;
    u = (u & 0x80000000u) ? (u ^ 0x80000000u) : ~u;
    thrOut[0] = __uint_as_float(u);
  }
}

// ======== fused column FFT * mask * column IFFT: role-major, barriered ========
__global__ __launch_bounds__(256) void colfft(v2f* __restrict__ freq,
                                              const float* __restrict__ rbuf, const float* __restrict__ thrp){
  __shared__ v4f wf[UU];
  __shared__ v2f cs13[13];
  __shared__ v2f buf[UU*17];
  { int i = threadIdx.x;
    const double PI2 = 6.283185307179586476925286766559;
    if (i < UU){
      double a = -PI2 * (double)i / (double)UU;
      float c = (float)cos(a), s = (float)sin(a);
      v4f f; f.x = c; f.y = s; f.z = -s; f.w = c; wf[i] = f;
    }
    if (i < 13){
      double a = PI2 * (double)i / 13.0;
      cs13[i] = mk2((float)cos(a), (float)sin(a));
    } }
  const int role = threadIdx.x >> 4, c = threadIdx.x & 15;
  const int img = blockIdx.x / 11;                // paired plane [0,128)
  const int v0 = (blockIdx.x - img*11) << 4;
  v2f* base = freq + (size_t)img * NPIX + v0 + c;
  const float thr = thrp[0];
  __syncthreads();
  // Phase A: inner 16-pt forward DFTs (n1 = role < 13) -> buf rows j*13+role
  if (role < 13){
    v2f v[16];
    #pragma unroll
    for (int a = 0; a < 16; a++) v[a] = base[(13*a + role)*VV];
    fft16<false>(v);
    #pragma unroll
    for (int j = 0; j < 16; j++)
      buf[(j*13 + role)*17 + c] = cmulw4(v[4*(j&3) + (j>>2)], wf[role*j]);
  }
  __syncthreads();
  // Phase B: 13-pt DFT (k1 = role), mask, stage in regs
  v2f F[13];
  {
    v2f t[13];
    #pragma unroll
    for (int n2 = 0; n2 < 13; n2++) t[n2] = buf[(role*13 + n2)*17 + c];
    dftN<13,false>(t, F, cs13);
    #pragma unroll
    for (int k2 = 0; k2 < 13; k2++){
      int u = role + 16*k2;
      float m = (rbuf[u*VV + v0 + c] > thr) ? 1.0f : 0.0f;
      F[k2] *= sp(m);
    }
  }
  __syncthreads();
  #pragma unroll
  for (int k2 = 0; k2 < 13; k2++) buf[(role + 16*k2)*17 + c] = F[k2];
  __syncthreads();
  // Phase C: inner 16-pt inverse DFTs
  if (role < 13){
    v2f v[16];
    #pragma unroll
    for (int a = 0; a < 16; a++) v[a] = buf[(13*a + role)*17 + c];
    fft16<true>(v);
    #pragma unroll
    for (int j = 0; j < 16; j++)
      buf[(j*13 + role)*17 + c] = cmulw4i(v[4*(j&3) + (j>>2)], wf[role*j]);
  }
  __syncthreads();
  // Phase D: 13-pt inverse DFT, write spatial column back (unscaled)
  {
    v2f t[13], G[13];
    #pragma unroll
    for (int n2 = 0; n2 < 13; n2++) t[n2] = buf[(role*13 + n2)*17 + c];
    dftN<13,true>(t, G, cs13);
    #pragma unroll
    for (int k2 = 0; k2 < 13; k2++)
      base[(role + 16*k2)*VV] = G[k2];
  }
}

// ======== row IFFT + split pair + abs + scale, wave-autonomous ========
__global__ __launch_bounds__(256) void rowifft_abs(const v2f* __restrict__ freq, float* __restrict__ out){
  __shared__ v4f wf[VV];
  __shared__ v2f cs11[11];
  __shared__ v2f mid[16][177];
  { int i = threadIdx.x;
    const double PI2 = 6.283185307179586476925286766559;
    if (i < VV){
      double a = -PI2 * (double)i / (double)VV;
      float c = (float)cos(a), s = (float)sin(a);
      v4f f; f.x = c; f.y = s; f.z = -s; f.w = c; wf[i] = f;
    }
    if (i < 11){
      double a = PI2 * (double)i / 11.0;
      cs11[i] = mk2((float)cos(a), (float)sin(a));
    } }
  const int gr = threadIdx.x >> 4, ln = threadIdx.x & 15;
  const int row = blockIdx.x * 16 + gr;
  const int p = row / UU, rr = row - p * UU;
  const v2f* fr = freq + (size_t)row * VV;
  float* orow1 = out + ((size_t)(2*p) * UU + rr) * VV;
  float* orow2 = orow1 + (size_t)NPIX;
  __syncthreads();
  if (ln < 11){
    v2f v[16];
    #pragma unroll
    for (int a = 0; a < 16; a++) v[a] = fr[11*a + ln];
    fft16<true>(v);
    #pragma unroll
    for (int j = 0; j < 16; j++)
      mid[gr][j*11 + ln] = cmulw4i(v[4*(j&3) + (j>>2)], wf[ln*j]);
  }
  v2f t[11], G[11];
  #pragma unroll
  for (int n2 = 0; n2 < 11; n2++) t[n2] = mid[gr][ln*11 + n2];
  dftN<11,true>(t, G, cs11);
  #pragma unroll
  for (int k2 = 0; k2 < 11; k2++){
    orow1[ln + 16*k2] = fabsf(G[k2].x) * (1.0f / 36608.0f);
    orow2[ln + 16*k2] = fabsf(G[k2].y) * (1.0f / 36608.0f);
  }
}

extern "C" void kernel_launch(void* const* d_in, const int* in_sizes, int n_in,
                              void* d_out, int out_size, void* d_ws, size_t ws_size,
                              hipStream_t stream){
  const float* x   = (const float*)d_in[0];   // (32,8,208,176) f32
  const float* kin = (const float*)d_in[1];   // (3,3,1,1) f32
  float* out = (float*)d_out;
  char* ws = (char*)d_ws;
  v2f*      freq = (v2f*)ws;                     // 37,486,592 B
  float*    rbuf = (float*)(ws + 37486592);      // 146,432 B
  float*    thr  = (float*)(ws + 37633024);      // 16 B
  unsigned* bins = (unsigned*)(ws + 37633040);   // 4*256 u32

  hipMemsetAsync(bins, 0, 4*256*4, stream);
  hipLaunchKernelGGL(rowfft_mask,  dim3(ROWBLKS + MASKBLKS), dim3(256), 0, stream, x, freq, kin, rbuf, bins);
  hipLaunchKernelGGL(hist_pass<1>, dim3(143),  dim3(256), 0, stream, rbuf, bins, bins + 256);
  hipLaunchKernelGGL(hist_pass<2>, dim3(143),  dim3(256), 0, stream, rbuf, bins, bins + 512);
  hipLaunchKernelGGL(hist_pass<3>, dim3(143),  dim3(256), 0, stream, rbuf, bins, bins + 768);
  hipLaunchKernelGGL(thr_final,    dim3(1),    dim3(256), 0, stream, bins, thr);
  hipLaunchKernelGGL(colfft,       dim3(1408), dim3(256), 0, stream, freq, rbuf, thr);
  hipLaunchKernelGGL(rowifft_abs,  dim3(1664), dim3(256), 0, stream, freq, out);
}